// Round 1
// 165.194 us; speedup vs baseline: 1.4099x; 1.4099x over previous
//
#include <hip/hip_runtime.h>
#include <hip/hip_bf16.h>

#define BS 16
#define TT 20
#define STEPS 12
#define NN 512
#define EE 64

typedef __attribute__((ext_vector_type(8))) short bfrag8;
typedef __attribute__((ext_vector_type(4))) float f32x4;
typedef unsigned short ushort_t;
typedef unsigned int uint_t;

#define MFMA16(a,b,c) __builtin_amdgcn_mfma_f32_16x16x32_bf16(a,b,c,0,0,0)

#if __has_builtin(__builtin_amdgcn_rcpf)
#define RCP(x) __builtin_amdgcn_rcpf(x)
#else
#define RCP(x) (1.0f/(x))
#endif

__device__ __forceinline__ float tanh_fast(float x) {
  float t = __expf(-2.f * fabsf(x));      // in (0,1]
  float r = (1.f - t) * RCP(1.f + t);
  return copysignf(r, x);
}

__device__ __forceinline__ float lrelu(float x) { return x > 0.f ? x : 0.01f * x; }

__device__ __forceinline__ float wsum64(float x) {
  #pragma unroll
  for (int off = 32; off > 0; off >>= 1) x += __shfl_xor(x, off);
  return x;
}

__device__ __forceinline__ ushort_t f2bf(float f) {   // RNE float->bf16
  uint_t u = __float_as_uint(f);
  u += 0x7fffu + ((u >> 16) & 1u);
  return (ushort_t)(u >> 16);
}

// ===========================================================================
// setup: crow[kb][tpos][p] = adj[kb][sk[tpos]][node_p]
//                          + (1/512) sum_m adj[kb][sk[tpos]][m] adj[kb][m][node_p]
// for tpos in 0..18, p in 0..19 (node_p = skill[b][p]).
// grid 128 = kb(32) x pq(4, 5 columns each), 256 threads.
// ===========================================================================
__global__ __launch_bounds__(256) void setup_kernel(
    const int* __restrict__ skill, const float* __restrict__ adj,
    float* __restrict__ crow)
{
  __shared__ __align__(16) float a_rows[19*516];
  __shared__ __align__(16) float a_cols[5*516];
  __shared__ float red[95*2];
  __shared__ int s_node[5];

  int tid = threadIdx.x, bid = blockIdx.x;
  int kb = bid >> 2, pq = bid & 3;
  int b = kb & 15;
  const float* A = adj + (size_t)kb*NN*NN;

  for (int idx = tid; idx < 19*512; idx += 256) {
    int tpos = idx >> 9, m = idx & 511;
    a_rows[tpos*516 + m] = A[(size_t)skill[b*TT + tpos]*NN + m];
  }
  if (tid < 5) s_node[tid] = skill[b*TT + pq*5 + tid];
  __syncthreads();
  for (int idx = tid; idx < 5*512; idx += 256) {
    int p = idx >> 9, m = idx & 511;
    a_cols[p*516 + m] = A[(size_t)m*NN + s_node[p]];
  }
  __syncthreads();

  int pr = tid & 127, mh = tid >> 7;
  if (pr < 95) {
    int tpos = pr / 5, p = pr % 5;
    const float4* ra = (const float4*)&a_rows[tpos*516 + mh*256];
    const float4* rc = (const float4*)&a_cols[p*516 + mh*256];
    float s = 0.f;
    #pragma unroll 8
    for (int i = 0; i < 64; ++i) {
      float4 x = ra[i], y = rc[i];
      s += x.x*y.x + x.y*y.y + x.z*y.z + x.w*y.w;
    }
    red[pr*2 + mh] = s;
  }
  __syncthreads();
  if (tid < 95) {
    int tpos = tid / 5, p = tid % 5;
    float dot = red[tid*2] + red[tid*2 + 1];
    crow[(size_t)kb*380 + tpos*20 + pq*5 + p] =
        a_rows[tpos*516 + s_node[p]] + dot * (1.f/512.f);
  }
}

// ===========================================================================
// step: ALL 12 recursion steps for one batch b in one block (512 threads).
// Tracked hidden = 20 skill-position rows, kept as bf16 in LDS.
// Per step: GEMM1 (v: 20 rows x W1b, u: 8 rows x W1a) -> tanh -> Pade
// tanh(u+v) -> m1[160x64] bf16 -> GEMM2 x W2 -> tanh*exp(-dt) -> crow-weighted
// l-sum -> new hidden rows (+ agg_tgt for target position t+8).
// ===========================================================================
__global__ __launch_bounds__(512) void step_kernel(
    const int* __restrict__ skill, const int* __restrict__ timeq,
    const int* __restrict__ label, const float* __restrict__ nemb,
    const float* __restrict__ W1, const float* __restrict__ W2,
    const float* __restrict__ b1, const float* __restrict__ b2,
    const float* __restrict__ crow, float* __restrict__ agg_tgt)
{
  __shared__ __align__(16) ushort_t sWa[64*72];
  __shared__ __align__(16) ushort_t sWb[64*72];
  __shared__ __align__(16) ushort_t sW2[64*72];
  __shared__ __align__(16) ushort_t sH[32*72];     // rows 0..19 hidden, 20..31 zero
  __shared__ __align__(16) float sTV[20*72];
  __shared__ __align__(16) float sTU[8*72];
  __shared__ __align__(16) ushort_t sM1[160*72];   // row p*8 + l
  __shared__ float sCROW[2*19*20];                 // [k][tpos][p]
  __shared__ float sED[STEPS*8];
  __shared__ int sSK[TT];

  int tid = threadIdx.x, b = blockIdx.x;
  int w = tid >> 6, lane = tid & 63, q = lane >> 4, nn = lane & 15;
  int ct = w & 3, half = w >> 2, epos = ct*16 + nn;

  if (tid < TT) sSK[tid] = skill[b*TT + tid];
  for (int idx = tid; idx < 4096; idx += 512) {
    int e = idx >> 6, j = idx & 63;
    sWa[e*72 + j] = f2bf(W1[e*128 + j]);         // hh side (u)
    sWb[e*72 + j] = f2bf(W1[e*128 + 64 + j]);    // hidden side (v)
    sW2[e*72 + j] = f2bf(W2[e*64 + j]);
  }
  for (int idx = tid; idx < 760; idx += 512) {
    int k = idx / 380, r2 = idx % 380;
    sCROW[idx] = crow[(size_t)(k*BS + b)*380 + r2];
  }
  if (tid < STEPS*8) {
    int s = tid >> 3, l = tid & 7;
    float d = fabsf((float)(timeq[b*TT + s + l] - timeq[b*TT + s + 8]));
    sED[tid] = expf(-logf(d + 1e-6f) * 0.6213349345596119f);
  }
  __syncthreads();                 // sSK / sW visible

  // h0: scatter-init restricted to tracked positions
  for (int idx = tid; idx < 32*64; idx += 512) {
    int p = idx >> 6, e = idx & 63;
    ushort_t hv = 0;
    if (p < 20) {
      int node = sSK[p];
      int lstar = -1;
      #pragma unroll
      for (int l = 0; l < 8; ++l) if (sSK[l] == node) lstar = l;
      if (lstar >= 0) {
        float lp = (label[b*TT + lstar] == 1) ? 1.f : -1.f;
        hv = f2bf(nemb[node*EE + e] * lp);
      }
    }
    sH[p*72 + e] = hv;
  }
  __syncthreads();

  // hoist weight B-fragments (constant across all steps)
  bfrag8 wb0 = *(const bfrag8*)&sWb[epos*72 + q*8];
  bfrag8 wb1 = *(const bfrag8*)&sWb[epos*72 + 32 + q*8];
  bfrag8 wa0 = *(const bfrag8*)&sWa[epos*72 + q*8];
  bfrag8 wa1 = *(const bfrag8*)&sWa[epos*72 + 32 + q*8];
  bfrag8 w20 = *(const bfrag8*)&sW2[epos*72 + q*8];
  bfrag8 w21 = *(const bfrag8*)&sW2[epos*72 + 32 + q*8];
  float b1v = b1[epos], b2v = b2[epos];

  for (int t = 0; t < STEPS; ++t) {
    // ---- GEMM1
    if (half == 0) {
      bfrag8 a0 = *(const bfrag8*)&sH[nn*72 + q*8];
      bfrag8 a1 = *(const bfrag8*)&sH[nn*72 + 32 + q*8];
      f32x4 accV = {0,0,0,0};
      accV = MFMA16(a0, wb0, accV);
      accV = MFMA16(a1, wb1, accV);
      int ur = (nn < 8) ? (t + nn) : 24;           // rows 24.. are zero
      bfrag8 u0 = *(const bfrag8*)&sH[ur*72 + q*8];
      bfrag8 u1 = *(const bfrag8*)&sH[ur*72 + 32 + q*8];
      f32x4 accU = {0,0,0,0};
      accU = MFMA16(u0, wa0, accU);
      accU = MFMA16(u1, wa1, accU);
      #pragma unroll
      for (int r = 0; r < 4; ++r)
        sTV[(q*4 + r)*72 + epos] = tanh_fast(accV[r]);
      if (q < 2) {
        #pragma unroll
        for (int r = 0; r < 4; ++r)
          sTU[(q*4 + r)*72 + epos] = tanh_fast(accU[r] + b1v);
      }
    } else {
      bfrag8 a0 = *(const bfrag8*)&sH[(16 + nn)*72 + q*8];
      bfrag8 a1 = *(const bfrag8*)&sH[(16 + nn)*72 + 32 + q*8];
      f32x4 accV = {0,0,0,0};
      accV = MFMA16(a0, wb0, accV);
      accV = MFMA16(a1, wb1, accV);
      if (q == 0) {
        #pragma unroll
        for (int r = 0; r < 4; ++r)
          sTV[(16 + r)*72 + epos] = tanh_fast(accV[r]);
      }
    }
    __syncthreads();

    // ---- Pade: m1[p*8+l] = tanh(u_l + v_p) as bf16
    {
      int pp = tid >> 5, ep = tid & 31;
      for (int p = pp; p < 20; p += 16) {
        float2 tv2 = *(const float2*)&sTV[p*72 + 2*ep];
        #pragma unroll
        for (int l = 0; l < 8; ++l) {
          float2 tu2 = *(const float2*)&sTU[l*72 + 2*ep];
          float2 num, den, m;
          num.x = tu2.x + tv2.x;            num.y = tu2.y + tv2.y;
          den.x = fmaf(tu2.x, tv2.x, 1.f);  den.y = fmaf(tu2.y, tv2.y, 1.f);
          den.x = fmaxf(den.x, 1e-30f);     den.y = fmaxf(den.y, 1e-30f);
          m.x = num.x * RCP(den.x);         m.y = num.y * RCP(den.y);
          __hip_bfloat162 h2 = __float22bfloat162_rn(m);
          *(__hip_bfloat162*)&sM1[(p*8 + l)*72 + 2*ep] = h2;
        }
      }
    }
    __syncthreads();

    // ---- GEMM2 + epilogue (warp-half rt split: half0 rt0..4, half1 rt5..9)
    const float* edt = &sED[t*8];
    #pragma unroll
    for (int rr = 0; rr < 5; ++rr) {
      int rt = half*5 + rr;
      bfrag8 a0 = *(const bfrag8*)&sM1[(rt*16 + nn)*72 + q*8];
      bfrag8 a1 = *(const bfrag8*)&sM1[(rt*16 + nn)*72 + 32 + q*8];
      f32x4 z = {0,0,0,0};
      z = MFMA16(a0, w20, z);
      z = MFMA16(a1, w21, z);
      int p = rt*2 + (q >> 1);
      float ag0 = 0.f, ag1 = 0.f;
      #pragma unroll
      for (int r = 0; r < 4; ++r) {
        int l = (q & 1)*4 + r;
        float m2 = tanh_fast(z[r] + b2v) * edt[l];
        ag0 = fmaf(sCROW[(t + l)*20 + p], m2, ag0);
        ag1 = fmaf(sCROW[380 + (t + l)*20 + p], m2, ag1);
      }
      ag0 += __shfl_xor(ag0, 16);     // combine the two l-halves (q ^ 1)
      ag1 += __shfl_xor(ag1, 16);
      if ((q & 1) == 0) {
        sH[p*72 + epos] = f2bf(0.5f*(ag0 + ag1));
        if (p == t + 8) {
          agg_tgt[((t*BS + b)*2 + 0)*EE + epos] = ag0;
          agg_tgt[((t*BS + b)*2 + 1)*EE + epos] = ag1;
        }
      }
    }
    __syncthreads();
  }
}

// ===========================================================================
// Head: 3 linears + 2 layernorms + softmax[...,1] on the 384 gathered rows.
// ===========================================================================
__global__ __launch_bounds__(64) void pred_kernel(
    const float* __restrict__ agg_tgt,
    const float* __restrict__ fw1, const float* __restrict__ fb1,
    const float* __restrict__ g1, const float* __restrict__ be1,
    const float* __restrict__ fw2, const float* __restrict__ fb2,
    const float* __restrict__ g2, const float* __restrict__ be2,
    const float* __restrict__ fw3, const float* __restrict__ fb3,
    float* __restrict__ out)
{
  int ts = blockIdx.x >> 4, b = blockIdx.x & 15;
  int e = threadIdx.x;
  __shared__ float sx[64];
  for (int k = 0; k < 2; ++k) {
    float x = agg_tgt[((ts*BS + b)*2 + k)*EE + e];
    sx[e] = x;
    __syncthreads();
    float y = fb1[e];
    for (int j = 0; j < 64; ++j) y = fmaf(sx[j], fw1[e*64 + j], y);
    float h1 = x + lrelu(y);
    float mean1 = wsum64(h1) * (1.f/64.f);
    float d1 = h1 - mean1;
    float var1 = wsum64(d1*d1) * (1.f/64.f);
    float xn = d1 * rsqrtf(var1 + 1e-5f) * g1[e] + be1[e];
    __syncthreads();
    sx[e] = xn;
    __syncthreads();
    float z = fb2[e];
    for (int j = 0; j < 64; ++j) z = fmaf(sx[j], fw2[e*64 + j], z);
    float h2 = h1 + lrelu(z);
    float mean2 = wsum64(h2) * (1.f/64.f);
    float d2 = h2 - mean2;
    float var2 = wsum64(d2*d2) * (1.f/64.f);
    float xn2 = d2 * rsqrtf(var2 + 1e-5f) * g2[e] + be2[e];
    float p0 = wsum64(xn2 * fw3[e]);
    float p1 = wsum64(xn2 * fw3[64 + e]);
    if (e == 0) {
      float l0 = p0 + fb3[0], l1 = p1 + fb3[1];
      out[(ts*BS + b)*2 + k] = 1.f / (1.f + expf(l0 - l1));
    }
    __syncthreads();
  }
}

extern "C" void kernel_launch(void* const* d_in, const int* in_sizes, int n_in,
                              void* d_out, int out_size, void* d_ws, size_t ws_size,
                              hipStream_t stream) {
  const int*   skill = (const int*)d_in[0];
  const int*   timeq = (const int*)d_in[1];
  const int*   label = (const int*)d_in[2];
  const float* adj   = (const float*)d_in[3];
  const float* nemb  = (const float*)d_in[4];
  const float* W1    = (const float*)d_in[5];
  const float* b1    = (const float*)d_in[6];
  const float* W2    = (const float*)d_in[7];
  const float* b2    = (const float*)d_in[8];
  float* out = (float*)d_out;

  float* crow    = (float*)d_ws;             // 32*19*20 = 12160 floats
  float* agg_tgt = crow + 32*380;            // 12*16*2*64 = 24576 floats

  setup_kernel<<<128, 256, 0, stream>>>(skill, adj, crow);
  step_kernel<<<16, 512, 0, stream>>>(skill, timeq, label, nemb, W1, W2,
                                      b1, b2, crow, agg_tgt);
  pred_kernel<<<STEPS*BS, 64, 0, stream>>>(agg_tgt,
      (const float*)d_in[9],  (const float*)d_in[10],
      (const float*)d_in[11], (const float*)d_in[12],
      (const float*)d_in[13], (const float*)d_in[14],
      (const float*)d_in[15], (const float*)d_in[16],
      (const float*)d_in[17], (const float*)d_in[18], out);
}

// Round 2
// 164.387 us; speedup vs baseline: 1.4168x; 1.0049x over previous
//
#include <hip/hip_runtime.h>
#include <hip/hip_bf16.h>

#define BS 16
#define TT 20
#define STEPS 12
#define NN 512
#define EE 64

typedef __attribute__((ext_vector_type(8))) short bfrag8;
typedef __attribute__((ext_vector_type(4))) float f32x4;
typedef unsigned short ushort_t;
typedef unsigned int uint_t;

#define MFMA16(a,b,c) __builtin_amdgcn_mfma_f32_16x16x32_bf16(a,b,c,0,0,0)

#if __has_builtin(__builtin_amdgcn_rcpf)
#define RCP(x) __builtin_amdgcn_rcpf(x)
#else
#define RCP(x) (1.0f/(x))
#endif

__device__ __forceinline__ float tanh_fast(float x) {
  float t = __expf(-2.f * fabsf(x));      // in (0,1]
  float r = (1.f - t) * RCP(1.f + t);
  return copysignf(r, x);
}

__device__ __forceinline__ float lrelu(float x) { return x > 0.f ? x : 0.01f * x; }

__device__ __forceinline__ float wsum64(float x) {
  #pragma unroll
  for (int off = 32; off > 0; off >>= 1) x += __shfl_xor(x, off);
  return x;
}

__device__ __forceinline__ ushort_t f2bf(float f) {   // RNE float->bf16
  uint_t u = __float_as_uint(f);
  u += 0x7fffu + ((u >> 16) & 1u);
  return (ushort_t)(u >> 16);
}

// ===========================================================================
// setup: crow[kb][tpos][p] = adj[kb][sk[tpos]][node_p]
//                          + (1/512) sum_m adj[kb][sk[tpos]][m] adj[kb][m][node_p]
// for tpos in 0..18, p in 0..19 (node_p = skill[b][p]).
// grid 128 = kb(32) x pq(4, 5 columns each), 256 threads.
// (kept at 128 blocks: the stride-2048B column gather needs the MLP of many
//  blocks; folding it into the 16-block step kernel would be ~8x slower.)
// ===========================================================================
__global__ __launch_bounds__(256) void setup_kernel(
    const int* __restrict__ skill, const float* __restrict__ adj,
    float* __restrict__ crow)
{
  __shared__ __align__(16) float a_rows[19*516];
  __shared__ __align__(16) float a_cols[5*516];
  __shared__ float red[95*2];
  __shared__ int s_node[5];

  int tid = threadIdx.x, bid = blockIdx.x;
  int kb = bid >> 2, pq = bid & 3;
  int b = kb & 15;
  const float* A = adj + (size_t)kb*NN*NN;

  for (int idx = tid; idx < 19*512; idx += 256) {
    int tpos = idx >> 9, m = idx & 511;
    a_rows[tpos*516 + m] = A[(size_t)skill[b*TT + tpos]*NN + m];
  }
  if (tid < 5) s_node[tid] = skill[b*TT + pq*5 + tid];
  __syncthreads();
  for (int idx = tid; idx < 5*512; idx += 256) {
    int p = idx >> 9, m = idx & 511;
    a_cols[p*516 + m] = A[(size_t)m*NN + s_node[p]];
  }
  __syncthreads();

  int pr = tid & 127, mh = tid >> 7;
  if (pr < 95) {
    int tpos = pr / 5, p = pr % 5;
    const float4* ra = (const float4*)&a_rows[tpos*516 + mh*256];
    const float4* rc = (const float4*)&a_cols[p*516 + mh*256];
    float s = 0.f;
    #pragma unroll 8
    for (int i = 0; i < 64; ++i) {
      float4 x = ra[i], y = rc[i];
      s += x.x*y.x + x.y*y.y + x.z*y.z + x.w*y.w;
    }
    red[pr*2 + mh] = s;
  }
  __syncthreads();
  if (tid < 95) {
    int tpos = tid / 5, p = tid % 5;
    float dot = red[tid*2] + red[tid*2 + 1];
    crow[(size_t)kb*380 + tpos*20 + pq*5 + p] =
        a_rows[tpos*516 + s_node[p]] + dot * (1.f/512.f);
  }
}

// ===========================================================================
// step+head: ALL 12 recursion steps AND the 24 head evaluations for one batch
// b in one block (512 threads).  Tracked hidden = 20 skill-position rows in
// LDS bf16.  agg target rows stay in LDS (sAGG); the head (3 linears + 2 LN
// + softmax[..,1]) runs on the block's 8 waves, 3 uniform rounds of 1 task
// each, with fw1/fw2 staged coalesced into LDS (stride-65 pad -> 2-way=free).
// ===========================================================================
__global__ __launch_bounds__(512) void step_kernel(
    const int* __restrict__ skill, const int* __restrict__ timeq,
    const int* __restrict__ label, const float* __restrict__ nemb,
    const float* __restrict__ W1, const float* __restrict__ W2,
    const float* __restrict__ b1, const float* __restrict__ b2,
    const float* __restrict__ crow,
    const float* __restrict__ fw1, const float* __restrict__ fb1,
    const float* __restrict__ g1, const float* __restrict__ be1,
    const float* __restrict__ fw2, const float* __restrict__ fb2,
    const float* __restrict__ g2, const float* __restrict__ be2,
    const float* __restrict__ fw3, const float* __restrict__ fb3,
    float* __restrict__ out)
{
  __shared__ __align__(16) ushort_t sWa[64*72];
  __shared__ __align__(16) ushort_t sWb[64*72];
  __shared__ __align__(16) ushort_t sW2[64*72];
  __shared__ __align__(16) ushort_t sH[32*72];     // rows 0..19 hidden, 20..31 zero
  __shared__ __align__(16) float sFP[28*72];       // rows 0..19 = tv, 20..27 = tu
                                                   // (head phase: reused as sXN)
  __shared__ __align__(16) ushort_t sM1[160*72];   // row p*8 + l (head: fwLDS)
  __shared__ float sCROW[2*19*20];                 // [k][tpos][p]
  __shared__ float sED[STEPS*8];
  __shared__ float sAGG[24*68];                    // [t*2+k][e]
  __shared__ int sSK[TT];

  int tid = threadIdx.x, b = blockIdx.x;
  int w = tid >> 6, lane = tid & 63, q = lane >> 4, nn = lane & 15;
  int ct = w & 3, half = w >> 2, epos = ct*16 + nn;

  if (tid < TT) sSK[tid] = skill[b*TT + tid];
  for (int idx = tid; idx < 4096; idx += 512) {
    int e = idx >> 6, j = idx & 63;
    sWa[e*72 + j] = f2bf(W1[e*128 + j]);         // hh side (u)
    sWb[e*72 + j] = f2bf(W1[e*128 + 64 + j]);    // hidden side (v)
    sW2[e*72 + j] = f2bf(W2[e*64 + j]);
  }
  for (int idx = tid; idx < 760; idx += 512) {
    int k = idx / 380, r2 = idx % 380;
    sCROW[idx] = crow[(size_t)(k*BS + b)*380 + r2];
  }
  if (tid < STEPS*8) {
    int s = tid >> 3, l = tid & 7;
    float d = fabsf((float)(timeq[b*TT + s + l] - timeq[b*TT + s + 8]));
    sED[tid] = expf(-logf(d + 1e-6f) * 0.6213349345596119f);
  }
  __syncthreads();                 // sSK / sW visible

  // h0: scatter-init restricted to tracked positions
  for (int idx = tid; idx < 32*64; idx += 512) {
    int p = idx >> 6, e = idx & 63;
    ushort_t hv = 0;
    if (p < 20) {
      int node = sSK[p];
      int lstar = -1;
      #pragma unroll
      for (int l = 0; l < 8; ++l) if (sSK[l] == node) lstar = l;
      if (lstar >= 0) {
        float lp = (label[b*TT + lstar] == 1) ? 1.f : -1.f;
        hv = f2bf(nemb[node*EE + e] * lp);
      }
    }
    sH[p*72 + e] = hv;
  }
  __syncthreads();

  // hoist weight B-fragments (constant across all steps)
  bfrag8 wb0 = *(const bfrag8*)&sWb[epos*72 + q*8];
  bfrag8 wb1 = *(const bfrag8*)&sWb[epos*72 + 32 + q*8];
  bfrag8 wa0 = *(const bfrag8*)&sWa[epos*72 + q*8];
  bfrag8 wa1 = *(const bfrag8*)&sWa[epos*72 + 32 + q*8];
  bfrag8 w20 = *(const bfrag8*)&sW2[epos*72 + q*8];
  bfrag8 w21 = *(const bfrag8*)&sW2[epos*72 + 32 + q*8];
  float b1v = b1[epos], b2v = b2[epos];

  for (int t = 0; t < STEPS; ++t) {
    // ---- GEMM1
    if (half == 0) {
      bfrag8 a0 = *(const bfrag8*)&sH[nn*72 + q*8];
      bfrag8 a1 = *(const bfrag8*)&sH[nn*72 + 32 + q*8];
      f32x4 accV = {0,0,0,0};
      accV = MFMA16(a0, wb0, accV);
      accV = MFMA16(a1, wb1, accV);
      int ur = (nn < 8) ? (t + nn) : 24;           // rows 24.. are zero
      bfrag8 u0 = *(const bfrag8*)&sH[ur*72 + q*8];
      bfrag8 u1 = *(const bfrag8*)&sH[ur*72 + 32 + q*8];
      f32x4 accU = {0,0,0,0};
      accU = MFMA16(u0, wa0, accU);
      accU = MFMA16(u1, wa1, accU);
      #pragma unroll
      for (int r = 0; r < 4; ++r)
        sFP[(q*4 + r)*72 + epos] = tanh_fast(accV[r]);
      if (q < 2) {
        #pragma unroll
        for (int r = 0; r < 4; ++r)
          sFP[(20 + q*4 + r)*72 + epos] = tanh_fast(accU[r] + b1v);
      }
    } else {
      bfrag8 a0 = *(const bfrag8*)&sH[(16 + nn)*72 + q*8];
      bfrag8 a1 = *(const bfrag8*)&sH[(16 + nn)*72 + 32 + q*8];
      f32x4 accV = {0,0,0,0};
      accV = MFMA16(a0, wb0, accV);
      accV = MFMA16(a1, wb1, accV);
      if (q == 0) {
        #pragma unroll
        for (int r = 0; r < 4; ++r)
          sFP[(16 + r)*72 + epos] = tanh_fast(accV[r]);
      }
    }
    __syncthreads();

    // ---- Pade: m1[p*8+l] = tanh(u_l + v_p) as bf16
    {
      int pp = tid >> 5, ep = tid & 31;
      for (int p = pp; p < 20; p += 16) {
        float2 tv2 = *(const float2*)&sFP[p*72 + 2*ep];
        #pragma unroll
        for (int l = 0; l < 8; ++l) {
          float2 tu2 = *(const float2*)&sFP[(20 + l)*72 + 2*ep];
          float2 num, den, m;
          num.x = tu2.x + tv2.x;            num.y = tu2.y + tv2.y;
          den.x = fmaf(tu2.x, tv2.x, 1.f);  den.y = fmaf(tu2.y, tv2.y, 1.f);
          den.x = fmaxf(den.x, 1e-30f);     den.y = fmaxf(den.y, 1e-30f);
          m.x = num.x * RCP(den.x);         m.y = num.y * RCP(den.y);
          __hip_bfloat162 h2 = __float22bfloat162_rn(m);
          *(__hip_bfloat162*)&sM1[(p*8 + l)*72 + 2*ep] = h2;
        }
      }
    }
    __syncthreads();

    // ---- GEMM2 + epilogue (warp-half rt split: half0 rt0..4, half1 rt5..9)
    const float* edt = &sED[t*8];
    #pragma unroll
    for (int rr = 0; rr < 5; ++rr) {
      int rt = half*5 + rr;
      bfrag8 a0 = *(const bfrag8*)&sM1[(rt*16 + nn)*72 + q*8];
      bfrag8 a1 = *(const bfrag8*)&sM1[(rt*16 + nn)*72 + 32 + q*8];
      f32x4 z = {0,0,0,0};
      z = MFMA16(a0, w20, z);
      z = MFMA16(a1, w21, z);
      int p = rt*2 + (q >> 1);
      float ag0 = 0.f, ag1 = 0.f;
      #pragma unroll
      for (int r = 0; r < 4; ++r) {
        int l = (q & 1)*4 + r;
        float m2 = tanh_fast(z[r] + b2v) * edt[l];
        ag0 = fmaf(sCROW[(t + l)*20 + p], m2, ag0);
        ag1 = fmaf(sCROW[380 + (t + l)*20 + p], m2, ag1);
      }
      ag0 += __shfl_xor(ag0, 16);     // combine the two l-halves (q ^ 1)
      ag1 += __shfl_xor(ag1, 16);
      if ((q & 1) == 0) {
        sH[p*72 + epos] = f2bf(0.5f*(ag0 + ag1));
        if (p == t + 8) {
          sAGG[(t*2 + 0)*68 + epos] = ag0;
          sAGG[(t*2 + 1)*68 + epos] = ag1;
        }
      }
    }
    __syncthreads();
  }

  // ======================= head (fused pred) =======================
  // 24 tasks = (t,k); task = round*8 + w; 3 uniform rounds over 8 waves.
  float* fwLDS = (float*)sM1;      // 64x65 f32 = 16.6 KB (sM1 is 23 KB)
  float* sXN   = sFP;              // 24x68 f32 = 6.5 KB (sFP is 8 KB)

  for (int idx = tid; idx < 4096; idx += 512)
    fwLDS[(idx >> 6)*65 + (idx & 63)] = fw1[idx];
  __syncthreads();

  int e = lane;
  float h1s[3];
  float fb1v = fb1[e], g1v = g1[e], be1v = be1[e];
  #pragma unroll
  for (int r3 = 0; r3 < 3; ++r3) {
    int task = r3*8 + w;
    const float* xv = &sAGG[task*68];
    float x = xv[e];
    float y = fb1v;
    for (int j = 0; j < 64; ++j) y = fmaf(xv[j], fwLDS[e*65 + j], y);
    float h1 = x + lrelu(y);
    float mean1 = wsum64(h1) * (1.f/64.f);
    float d1 = h1 - mean1;
    float var1 = wsum64(d1*d1) * (1.f/64.f);
    float xn = d1 * rsqrtf(var1 + 1e-5f) * g1v + be1v;
    sXN[task*68 + e] = xn;
    h1s[r3] = h1;
  }
  __syncthreads();                 // all xn written, fw1 reads done

  for (int idx = tid; idx < 4096; idx += 512)
    fwLDS[(idx >> 6)*65 + (idx & 63)] = fw2[idx];
  __syncthreads();

  float fb2v = fb2[e], g2v = g2[e], be2v = be2[e];
  float w3a = fw3[e], w3b = fw3[64 + e];
  float fb30 = fb3[0], fb31 = fb3[1];
  #pragma unroll
  for (int r3 = 0; r3 < 3; ++r3) {
    int task = r3*8 + w;
    const float* xnv = &sXN[task*68];
    float z = fb2v;
    for (int j = 0; j < 64; ++j) z = fmaf(xnv[j], fwLDS[e*65 + j], z);
    float h2 = h1s[r3] + lrelu(z);
    float mean2 = wsum64(h2) * (1.f/64.f);
    float d2 = h2 - mean2;
    float var2 = wsum64(d2*d2) * (1.f/64.f);
    float xn2 = d2 * rsqrtf(var2 + 1e-5f) * g2v + be2v;
    float p0 = wsum64(xn2 * w3a);
    float p1 = wsum64(xn2 * w3b);
    if (e == 0) {
      int ts = task >> 1, kk = task & 1;
      float l0 = p0 + fb30, l1 = p1 + fb31;
      out[(ts*BS + b)*2 + kk] = 1.f / (1.f + expf(l0 - l1));
    }
  }
}

extern "C" void kernel_launch(void* const* d_in, const int* in_sizes, int n_in,
                              void* d_out, int out_size, void* d_ws, size_t ws_size,
                              hipStream_t stream) {
  const int*   skill = (const int*)d_in[0];
  const int*   timeq = (const int*)d_in[1];
  const int*   label = (const int*)d_in[2];
  const float* adj   = (const float*)d_in[3];
  const float* nemb  = (const float*)d_in[4];
  const float* W1    = (const float*)d_in[5];
  const float* b1    = (const float*)d_in[6];
  const float* W2    = (const float*)d_in[7];
  const float* b2    = (const float*)d_in[8];
  float* out = (float*)d_out;

  float* crow = (float*)d_ws;                // 32*19*20 = 12160 floats

  setup_kernel<<<128, 256, 0, stream>>>(skill, adj, crow);
  step_kernel<<<16, 512, 0, stream>>>(skill, timeq, label, nemb, W1, W2,
      b1, b2, crow,
      (const float*)d_in[9],  (const float*)d_in[10],
      (const float*)d_in[11], (const float*)d_in[12],
      (const float*)d_in[13], (const float*)d_in[14],
      (const float*)d_in[15], (const float*)d_in[16],
      (const float*)d_in[17], (const float*)d_in[18], out);
}

// Round 7
// 157.364 us; speedup vs baseline: 1.4800x; 1.0446x over previous
//
#include <hip/hip_runtime.h>
#include <hip/hip_bf16.h>

#define BS 16
#define TT 20
#define STEPS 12
#define NN 512
#define EE 64

typedef __attribute__((ext_vector_type(8))) short bfrag8;
typedef __attribute__((ext_vector_type(4))) float f32x4;
typedef unsigned short ushort_t;
typedef unsigned int uint_t;

#define MFMA16(a,b,c) __builtin_amdgcn_mfma_f32_16x16x32_bf16(a,b,c,0,0,0)

#if __has_builtin(__builtin_amdgcn_rcpf)
#define RCP(x) __builtin_amdgcn_rcpf(x)
#else
#define RCP(x) (1.0f/(x))
#endif

#if __has_builtin(__builtin_amdgcn_exp2f)
#define EXP2F(x) __builtin_amdgcn_exp2f(x)
#else
#define EXP2F(x) exp2f(x)
#endif

// tanh(x) = 1 - 2/(1+e^{2x}); 5 VALU ops, full-range safe:
// exp2->+inf => 1, exp2->0 => -1, monotone, ~1ulp from libm.
__device__ __forceinline__ float tanh_fast(float x) {
  float t = EXP2F(x * 2.8853900817779268f);   // e^{2x}
  return 1.f - 2.f * RCP(1.f + t);
}

__device__ __forceinline__ float lrelu(float x) { return x > 0.f ? x : 0.01f * x; }

__device__ __forceinline__ float wsum64(float x) {
  #pragma unroll
  for (int off = 32; off > 0; off >>= 1) x += __shfl_xor(x, off);
  return x;
}

__device__ __forceinline__ ushort_t f2bf(float f) {   // RNE float->bf16
  uint_t u = __float_as_uint(f);
  u += 0x7fffu + ((u >> 16) & 1u);
  return (ushort_t)(u >> 16);
}

// Pade combine: tanh(u+v) = (tu+tv)/(1+tu*tv), 2 elems -> packed bf16x2
__device__ __forceinline__ __hip_bfloat162 pade2(float2 tv, float2 tu) {
  float nx = tu.x + tv.x, ny = tu.y + tv.y;
  float dx = fmaf(tu.x, tv.x, 1.f), dy = fmaf(tu.y, tv.y, 1.f);
  dx = fmaxf(dx, 1e-30f); dy = fmaxf(dy, 1e-30f);
  float2 m; m.x = nx * RCP(dx); m.y = ny * RCP(dy);
  return __float22bfloat162_rn(m);
}

// ===========================================================================
// setup: crow[kb][tpos][p] = adj[kb][sk[tpos]][node_p]
//                          + (1/512) sum_m adj[kb][sk[tpos]][m] adj[kb][m][node_p]
// grid 128 = kb(32) x pq(4, 5 columns each), 256 threads.  (unchanged)
// ===========================================================================
__global__ __launch_bounds__(256) void setup_kernel(
    const int* __restrict__ skill, const float* __restrict__ adj,
    float* __restrict__ crow)
{
  __shared__ __align__(16) float a_rows[19*516];
  __shared__ __align__(16) float a_cols[5*516];
  __shared__ float red[95*2];
  __shared__ int s_node[5];

  int tid = threadIdx.x, bid = blockIdx.x;
  int kb = bid >> 2, pq = bid & 3;
  int b = kb & 15;
  const float* A = adj + (size_t)kb*NN*NN;

  for (int idx = tid; idx < 19*512; idx += 256) {
    int tpos = idx >> 9, m = idx & 511;
    a_rows[tpos*516 + m] = A[(size_t)skill[b*TT + tpos]*NN + m];
  }
  if (tid < 5) s_node[tid] = skill[b*TT + pq*5 + tid];
  __syncthreads();
  for (int idx = tid; idx < 5*512; idx += 256) {
    int p = idx >> 9, m = idx & 511;
    a_cols[p*516 + m] = A[(size_t)m*NN + s_node[p]];
  }
  __syncthreads();

  int pr = tid & 127, mh = tid >> 7;
  if (pr < 95) {
    int tpos = pr / 5, p = pr % 5;
    const float4* ra = (const float4*)&a_rows[tpos*516 + mh*256];
    const float4* rc = (const float4*)&a_cols[p*516 + mh*256];
    float s = 0.f;
    #pragma unroll 8
    for (int i = 0; i < 64; ++i) {
      float4 x = ra[i], y = rc[i];
      s += x.x*y.x + x.y*y.y + x.z*y.z + x.w*y.w;
    }
    red[pr*2 + mh] = s;
  }
  __syncthreads();
  if (tid < 95) {
    int tpos = tid / 5, p = tid % 5;
    float dot = red[tid*2] + red[tid*2 + 1];
    crow[(size_t)kb*380 + tpos*20 + pq*5 + p] =
        a_rows[tpos*516 + s_node[p]] + dot * (1.f/512.f);
  }
}

// ===========================================================================
// step+head, one block (512 thr, 8 warps) per batch.
// Per step (2 barriers): phase A = GEMM1 -> tanh(v) rows 0..19, tanh(u) l 0..7;
// phase B = per-warp whole tiles: in-register Pade -> A-frags -> 8 MFMAs
// (4 col-groups x 2 k) -> tanh*ed -> crow l-reduce -> sH rows [p0, 19].
// Dead-row pruning: at step t only rows p in [t+1,19] are updated (t=11: {19}).
// Head runs on prestaged LDS weights.
// ===========================================================================
__global__ __launch_bounds__(512) void step_kernel(
    const int* __restrict__ skill, const int* __restrict__ timeq,
    const int* __restrict__ label, const float* __restrict__ nemb,
    const float* __restrict__ W1, const float* __restrict__ W2,
    const float* __restrict__ b1, const float* __restrict__ b2,
    const float* __restrict__ crow,
    const float* __restrict__ fw1, const float* __restrict__ fb1,
    const float* __restrict__ g1, const float* __restrict__ be1,
    const float* __restrict__ fw2, const float* __restrict__ fb2,
    const float* __restrict__ g2, const float* __restrict__ be2,
    const float* __restrict__ fw3, const float* __restrict__ fb3,
    float* __restrict__ out)
{
  __shared__ __align__(16) ushort_t sWa[64*72];
  __shared__ __align__(16) ushort_t sWb[64*72];
  __shared__ __align__(16) ushort_t sW2[64*72];
  __shared__ __align__(16) ushort_t sH[32*72];     // rows 0..19 hidden, 20..31 zero
  __shared__ __align__(16) float sTV[20*72];
  __shared__ __align__(16) float sTU[8*72];
  __shared__ float sCROW[2*19*20];                 // [k][tpos][p]
  __shared__ float sED[STEPS*8];
  __shared__ float sAGG[24*68];                    // [t*2+k][e]
  __shared__ float sXN[24*68];
  __shared__ __align__(16) float fwL1[64*66];
  __shared__ __align__(16) float fwL2[64*66];
  __shared__ int sSK[TT];

  int tid = threadIdx.x, b = blockIdx.x;
  int w = tid >> 6, lane = tid & 63, q = lane >> 4, nn = lane & 15;
  int ct = w & 3, half = w >> 2, epos = ct*16 + nn;

  if (tid < TT) sSK[tid] = skill[b*TT + tid];
  for (int idx = tid; idx < 4096; idx += 512) {
    int e = idx >> 6, j = idx & 63;
    sWa[e*72 + j] = f2bf(W1[e*128 + j]);         // hh side (u)
    sWb[e*72 + j] = f2bf(W1[e*128 + 64 + j]);    // hidden side (v)
    sW2[e*72 + j] = f2bf(W2[e*64 + j]);
    fwL1[e*66 + j] = fw1[idx];
    fwL2[e*66 + j] = fw2[idx];
  }
  for (int idx = tid; idx < 760; idx += 512)
    sCROW[idx] = crow[(size_t)((idx/380)*BS + b)*380 + (idx%380)];
  if (tid < STEPS*8) {
    int s = tid >> 3, l = tid & 7;
    float d = fabsf((float)(timeq[b*TT + s + l] - timeq[b*TT + s + 8]));
    sED[tid] = expf(-logf(d + 1e-6f) * 0.6213349345596119f);
  }
  __syncthreads();                 // sSK / weights visible

  // h0: scatter-init restricted to tracked positions
  for (int idx = tid; idx < 32*64; idx += 512) {
    int p = idx >> 6, e = idx & 63;
    ushort_t hv = 0;
    if (p < 20) {
      int node = sSK[p];
      int lstar = -1;
      #pragma unroll
      for (int l = 0; l < 8; ++l) if (sSK[l] == node) lstar = l;
      if (lstar >= 0) {
        float lp = (label[b*TT + lstar] == 1) ? 1.f : -1.f;
        hv = f2bf(nemb[node*EE + e] * lp);
      }
    }
    sH[p*72 + e] = hv;
  }
  __syncthreads();

  // constant-per-thread fragments
  bfrag8 wb0 = *(const bfrag8*)&sWb[epos*72 + q*8];
  bfrag8 wb1 = *(const bfrag8*)&sWb[epos*72 + 32 + q*8];
  bfrag8 wa0 = *(const bfrag8*)&sWa[epos*72 + q*8];
  bfrag8 wa1 = *(const bfrag8*)&sWa[epos*72 + 32 + q*8];
  bfrag8 w200 = *(const bfrag8*)&sW2[(0*16+nn)*72 + q*8];
  bfrag8 w201 = *(const bfrag8*)&sW2[(0*16+nn)*72 + 32 + q*8];
  bfrag8 w210 = *(const bfrag8*)&sW2[(1*16+nn)*72 + q*8];
  bfrag8 w211 = *(const bfrag8*)&sW2[(1*16+nn)*72 + 32 + q*8];
  bfrag8 w220 = *(const bfrag8*)&sW2[(2*16+nn)*72 + q*8];
  bfrag8 w221 = *(const bfrag8*)&sW2[(2*16+nn)*72 + 32 + q*8];
  bfrag8 w230 = *(const bfrag8*)&sW2[(3*16+nn)*72 + q*8];
  bfrag8 w231 = *(const bfrag8*)&sW2[(3*16+nn)*72 + 32 + q*8];
  float b1v = b1[epos];
  float b2v0 = b2[nn], b2v1 = b2[16+nn], b2v2 = b2[32+nn], b2v3 = b2[48+nn];
  const bfrag8 ZB = {0,0,0,0,0,0,0,0};

  for (int t = 0; t < STEPS; ++t) {
    int p0 = (t == 11) ? 19 : t + 1;
    int R  = (t == 11) ? 1  : 19 - t;
    int ntiles = (R + 1) >> 1;

    // ---- phase A: GEMM1 -> sTV (v rows 0..19), sTU (u rows 0..7)
    if (half == 0) {
      bfrag8 a0 = *(const bfrag8*)&sH[nn*72 + q*8];
      bfrag8 a1 = *(const bfrag8*)&sH[nn*72 + 32 + q*8];
      f32x4 accV = {0,0,0,0};
      accV = MFMA16(a0, wb0, accV);
      accV = MFMA16(a1, wb1, accV);
      int ur = (nn < 8) ? (t + nn) : 24;           // rows 24.. are zero
      bfrag8 u0 = *(const bfrag8*)&sH[ur*72 + q*8];
      bfrag8 u1 = *(const bfrag8*)&sH[ur*72 + 32 + q*8];
      f32x4 accU = {0,0,0,0};
      accU = MFMA16(u0, wa0, accU);
      accU = MFMA16(u1, wa1, accU);
      #pragma unroll
      for (int r = 0; r < 4; ++r)
        sTV[(q*4 + r)*72 + epos] = tanh_fast(accV[r]);
      if (q < 2) {
        #pragma unroll
        for (int r = 0; r < 4; ++r)
          sTU[(q*4 + r)*72 + epos] = tanh_fast(accU[r] + b1v);
      }
    } else {
      bfrag8 a0 = *(const bfrag8*)&sH[(16 + nn)*72 + q*8];
      bfrag8 a1 = *(const bfrag8*)&sH[(16 + nn)*72 + 32 + q*8];
      f32x4 accV = {0,0,0,0};
      accV = MFMA16(a0, wb0, accV);
      accV = MFMA16(a1, wb1, accV);
      if (q == 0) {
        #pragma unroll
        for (int r = 0; r < 4; ++r)
          sTV[(16 + r)*72 + epos] = tanh_fast(accV[r]);
      }
    }
    __syncthreads();

    // ---- phase B: per-warp whole tiles, in-register Pade -> MFMA -> epilogue
    for (int rt = w; rt < ntiles; rt += 8) {
      int i = rt*2 + (nn >> 3);       // A-row block (relative p index)
      int lA = nn & 7;
      bfrag8 a0 = ZB, a1 = ZB;
      if (i < R) {
        int p = p0 + i;
        const float2* tvlo = (const float2*)&sTV[p*72 + q*8];
        const float2* tvhi = (const float2*)&sTV[p*72 + 32 + q*8];
        const float2* tulo = (const float2*)&sTU[lA*72 + q*8];
        const float2* tuhi = (const float2*)&sTU[lA*72 + 32 + q*8];
        union { bfrag8 v; __hip_bfloat162 h[4]; } A0, A1;
        #pragma unroll
        for (int j = 0; j < 4; ++j) {
          A0.h[j] = pade2(tvlo[j], tulo[j]);
          A1.h[j] = pade2(tvhi[j], tuhi[j]);
        }
        a0 = A0.v; a1 = A1.v;
      }
      f32x4 z0 = {0,0,0,0}, z1 = {0,0,0,0}, z2 = {0,0,0,0}, z3 = {0,0,0,0};
      z0 = MFMA16(a0, w200, z0);  z0 = MFMA16(a1, w201, z0);
      z1 = MFMA16(a0, w210, z1);  z1 = MFMA16(a1, w211, z1);
      z2 = MFMA16(a0, w220, z2);  z2 = MFMA16(a1, w221, z2);
      z3 = MFMA16(a0, w230, z3);  z3 = MFMA16(a1, w231, z3);

      int pi = rt*2 + (q >> 1);       // D-row block (relative p index)
      int p = p0 + pi;
      int psafe = (pi < R) ? p : p0;  // keep LDS reads in range
      float ag00=0,ag01=0,ag02=0,ag03=0, ag10=0,ag11=0,ag12=0,ag13=0;
      #pragma unroll
      for (int r = 0; r < 4; ++r) {
        int l = (q & 1)*4 + r;
        float c0 = sCROW[(t + l)*20 + psafe];
        float c1 = sCROW[380 + (t + l)*20 + psafe];
        float ed = sED[t*8 + l];
        float m;
        m = tanh_fast(z0[r] + b2v0) * ed; ag00 = fmaf(c0,m,ag00); ag10 = fmaf(c1,m,ag10);
        m = tanh_fast(z1[r] + b2v1) * ed; ag01 = fmaf(c0,m,ag01); ag11 = fmaf(c1,m,ag11);
        m = tanh_fast(z2[r] + b2v2) * ed; ag02 = fmaf(c0,m,ag02); ag12 = fmaf(c1,m,ag12);
        m = tanh_fast(z3[r] + b2v3) * ed; ag03 = fmaf(c0,m,ag03); ag13 = fmaf(c1,m,ag13);
      }
      ag00 += __shfl_xor(ag00,16); ag01 += __shfl_xor(ag01,16);
      ag02 += __shfl_xor(ag02,16); ag03 += __shfl_xor(ag03,16);
      ag10 += __shfl_xor(ag10,16); ag11 += __shfl_xor(ag11,16);
      ag12 += __shfl_xor(ag12,16); ag13 += __shfl_xor(ag13,16);
      if ((q & 1) == 0 && pi < R) {
        sH[p*72 +      nn] = f2bf(0.5f*(ag00 + ag10));
        sH[p*72 + 16 + nn] = f2bf(0.5f*(ag01 + ag11));
        sH[p*72 + 32 + nn] = f2bf(0.5f*(ag02 + ag12));
        sH[p*72 + 48 + nn] = f2bf(0.5f*(ag03 + ag13));
        if (p == t + 8) {
          sAGG[(t*2 + 0)*68 +      nn] = ag00;
          sAGG[(t*2 + 0)*68 + 16 + nn] = ag01;
          sAGG[(t*2 + 0)*68 + 32 + nn] = ag02;
          sAGG[(t*2 + 0)*68 + 48 + nn] = ag03;
          sAGG[(t*2 + 1)*68 +      nn] = ag10;
          sAGG[(t*2 + 1)*68 + 16 + nn] = ag11;
          sAGG[(t*2 + 1)*68 + 32 + nn] = ag12;
          sAGG[(t*2 + 1)*68 + 48 + nn] = ag13;
        }
      }
    }
    __syncthreads();
  }

  // ======================= head (fused pred) =======================
  // 24 tasks = (t,k); task = round*8 + w; weights prestaged in fwL1/fwL2.
  int e = lane;
  float h1s[3];
  float fb1v = fb1[e], g1v = g1[e], be1v = be1[e];
  #pragma unroll
  for (int r3 = 0; r3 < 3; ++r3) {
    int task = r3*8 + w;
    const float* xv = &sAGG[task*68];
    const float2* xv2 = (const float2*)xv;
    const float2* wp  = (const float2*)&fwL1[e*66];
    float x = xv[e];
    float y0 = fb1v, y1 = 0.f;
    #pragma unroll
    for (int j = 0; j < 32; j += 2) {
      float2 a  = xv2[j];     float2 bb = wp[j];
      y0 = fmaf(a.x, bb.x, y0);  y0 = fmaf(a.y, bb.y, y0);
      float2 a2 = xv2[j+1];   float2 b2f = wp[j+1];
      y1 = fmaf(a2.x, b2f.x, y1);  y1 = fmaf(a2.y, b2f.y, y1);
    }
    float h1 = x + lrelu(y0 + y1);
    float mean1 = wsum64(h1) * (1.f/64.f);
    float d1 = h1 - mean1;
    float var1 = wsum64(d1*d1) * (1.f/64.f);
    float xn = d1 * rsqrtf(var1 + 1e-5f) * g1v + be1v;
    sXN[task*68 + e] = xn;
    h1s[r3] = h1;
  }
  __syncthreads();                 // all xn written

  float fb2v = fb2[e], g2v = g2[e], be2v = be2[e];
  float w3a = fw3[e], w3b = fw3[64 + e];
  float fb30 = fb3[0], fb31 = fb3[1];
  #pragma unroll
  for (int r3 = 0; r3 < 3; ++r3) {
    int task = r3*8 + w;
    const float2* xn2v = (const float2*)&sXN[task*68];
    const float2* wp   = (const float2*)&fwL2[e*66];
    float z0 = fb2v, z1 = 0.f;
    #pragma unroll
    for (int j = 0; j < 32; j += 2) {
      float2 a  = xn2v[j];    float2 bb = wp[j];
      z0 = fmaf(a.x, bb.x, z0);  z0 = fmaf(a.y, bb.y, z0);
      float2 a2 = xn2v[j+1];  float2 b2f = wp[j+1];
      z1 = fmaf(a2.x, b2f.x, z1);  z1 = fmaf(a2.y, b2f.y, z1);
    }
    float h2 = h1s[r3] + lrelu(z0 + z1);
    float mean2 = wsum64(h2) * (1.f/64.f);
    float d2 = h2 - mean2;
    float var2 = wsum64(d2*d2) * (1.f/64.f);
    float xn2 = d2 * rsqrtf(var2 + 1e-5f) * g2v + be2v;
    float p0s = wsum64(xn2 * w3a);
    float p1s = wsum64(xn2 * w3b);
    if (e == 0) {
      int ts = task >> 1, kk = task & 1;
      float l0 = p0s + fb30, l1 = p1s + fb31;
      out[(ts*BS + b)*2 + kk] = 1.f / (1.f + expf(l0 - l1));
    }
  }
}

extern "C" void kernel_launch(void* const* d_in, const int* in_sizes, int n_in,
                              void* d_out, int out_size, void* d_ws, size_t ws_size,
                              hipStream_t stream) {
  const int*   skill = (const int*)d_in[0];
  const int*   timeq = (const int*)d_in[1];
  const int*   label = (const int*)d_in[2];
  const float* adj   = (const float*)d_in[3];
  const float* nemb  = (const float*)d_in[4];
  const float* W1    = (const float*)d_in[5];
  const float* b1    = (const float*)d_in[6];
  const float* W2    = (const float*)d_in[7];
  const float* b2    = (const float*)d_in[8];
  float* out = (float*)d_out;

  float* crow = (float*)d_ws;                // 32*19*20 = 12160 floats

  setup_kernel<<<128, 256, 0, stream>>>(skill, adj, crow);
  step_kernel<<<16, 512, 0, stream>>>(skill, timeq, label, nemb, W1, W2,
      b1, b2, crow,
      (const float*)d_in[9],  (const float*)d_in[10],
      (const float*)d_in[11], (const float*)d_in[12],
      (const float*)d_in[13], (const float*)d_in[14],
      (const float*)d_in[15], (const float*)d_in[16],
      (const float*)d_in[17], (const float*)d_in[18], out);
}